// Round 1
// baseline (451.794 us; speedup 1.0000x reference)
//
#include <hip/hip_runtime.h>

// BasicNCA: x:(16,1,512,512) f32, k:(1,1,3,3), w1:(10,1), b1:(10), w2:(1,10), steps=16
// out: (steps+1, 16, 1, 512, 512) f32 — state trajectory incl. initial state.
//
// Each step: s = conv3x3_same(x,k); g = exp(-(s-1)^2);
//            y = sigmoid(sum_o w2[o]*relu(w1[o]*g+b1[o])); x' = x + y - 0.5
// Steps are sequentially dependent (stencil halo) -> one kernel per step on the
// stream; slice t is read, slice t+1 written, all inside d_out.

#define NCA_H 512
#define NCA_W 512
#define NCA_HW (NCA_H * NCA_W)

__global__ __launch_bounds__(256) void nca_step(const float* __restrict__ src,
                                                float* __restrict__ dst,
                                                const float* __restrict__ kc,
                                                const float* __restrict__ w1,
                                                const float* __restrict__ b1,
                                                const float* __restrict__ w2) {
    __shared__ float sk[9], sw1[10], sb1[10], sw2[10];
    {
        int t = threadIdx.x;
        if (t < 9)  sk[t]  = kc[t];
        if (t < 10) { sw1[t] = w1[t]; sb1[t] = b1[t]; sw2[t] = w2[t]; }
    }
    __syncthreads();

    // one thread = 4 contiguous pixels along W
    int idx = blockIdx.x * blockDim.x + threadIdx.x;    // 0 .. B*H*W/4 - 1
    int wq = idx & 127;            // W/4 = 128 groups per row
    int h  = (idx >> 7) & 511;
    int b  = idx >> 16;            // 128*512 = 65536
    int w0 = wq << 2;

    const float* base = src + (size_t)b * NCA_HW;

    // rowv[r][c]: rows h-1..h+1, columns w0-1 .. w0+4 (c = col - (w0-1))
    float rowv[3][6];
#pragma unroll
    for (int r = 0; r < 3; ++r) {
        int hh = h + r - 1;
        if (hh < 0 || hh >= NCA_H) {
#pragma unroll
            for (int c = 0; c < 6; ++c) rowv[r][c] = 0.f;
        } else {
            const float* rp = base + hh * NCA_W + w0;   // 16B aligned (w0 % 4 == 0)
            float4 c4 = *(const float4*)rp;
            rowv[r][1] = c4.x; rowv[r][2] = c4.y; rowv[r][3] = c4.z; rowv[r][4] = c4.w;
            rowv[r][0] = (w0 > 0) ? rp[-1] : 0.f;
            rowv[r][5] = (w0 + 4 < NCA_W) ? rp[4] : 0.f;
        }
    }

    float4 res;
    float* resp = (float*)&res;
#pragma unroll
    for (int j = 0; j < 4; ++j) {
        float s = 0.f;
#pragma unroll
        for (int r = 0; r < 3; ++r) {
            s = fmaf(sk[r * 3 + 0], rowv[r][j],     s);
            s = fmaf(sk[r * 3 + 1], rowv[r][j + 1], s);
            s = fmaf(sk[r * 3 + 2], rowv[r][j + 2], s);
        }
        float d = s - 1.0f;
        float g = __expf(-d * d);
        float acc = 0.f;
#pragma unroll
        for (int o = 0; o < 10; ++o) {
            float hm = fmaxf(fmaf(sw1[o], g, sb1[o]), 0.f);
            acc = fmaf(sw2[o], hm, acc);
        }
        float sig = __fdividef(1.0f, 1.0f + __expf(-acc));
        resp[j] = rowv[1][j + 1] + (sig - 0.5f);   // residual: x + (y - 0.5)
    }

    *(float4*)(dst + (size_t)b * NCA_HW + h * NCA_W + w0) = res;
}

extern "C" void kernel_launch(void* const* d_in, const int* in_sizes, int n_in,
                              void* d_out, int out_size, void* d_ws, size_t ws_size,
                              hipStream_t stream) {
    const float* x  = (const float*)d_in[0];
    const float* k  = (const float*)d_in[1];
    const float* w1 = (const float*)d_in[2];
    const float* b1 = (const float*)d_in[3];
    const float* w2 = (const float*)d_in[4];
    float* out = (float*)d_out;

    const int slice = in_sizes[0];                 // 16*512*512 = 4194304
    const int steps = out_size / slice - 1;        // 16

    // slice 0 = initial state
    hipMemcpyAsync(out, x, (size_t)slice * sizeof(float),
                   hipMemcpyDeviceToDevice, stream);

    const int threads = 256;
    const int blocks  = slice / 4 / threads;       // 4096
    for (int t = 0; t < steps; ++t) {
        nca_step<<<blocks, threads, 0, stream>>>(out + (size_t)t * slice,
                                                 out + (size_t)(t + 1) * slice,
                                                 k, w1, b1, w2);
    }
}